// Round 2
// baseline (27858.139 us; speedup 1.0000x reference)
//
#include <hip/hip_runtime.h>
#include <stdint.h>

// ---------------- problem constants ----------------
#define T_STEPS 1000
#define B_SZ    32
#define NI      512
#define NH      1024
#define NO      256

// R8 scan decomposition (gather identical to R7, sync rebuilt):
//   block (jg, bg): j in [32*jg, 32*jg+32) for batches [4*bg, 4*bg+4).
//   bid = jg*8 + bg  => all 32 blocks of group bg share bid%8 == bg, i.e. one
//   XCD under the measured round-robin mapping. Communication is group-local
//   (batches are independent), so sync can stay inside one XCD's L2 via sc0
//   (SE-scope: L1-bypass, L2-served) instead of agent-scope (sc1 = MALL every
//   spin -- R7's regression). Correctness does NOT assume the mapping: a
//   one-time agent-scope handshake verifies co-location per group; mismatch
//   falls back to agent-scope sync. A bounded-spin escalation (sc0 -> agent)
//   makes a wrong fast-path choice unable to hang.
#define JBLK    32
#define BBATCH  4
#define NJG     (NH / JBLK)       // 32
#define NBG     (B_SZ / BBATCH)   // 8
#define NBLK    (NJG * NBG)       // 256

typedef unsigned long long u64;

// ---------------- ws layout (bytes) ----------------
#define OFF_IEXT 0ull
#define SZ_IEXT  ((u64)T_STEPS * B_SZ * NH * 4ull)   // 131,072,000
#define OFF_RATE (OFF_IEXT + SZ_IEXT)
#define SZ_RATE  ((u64)B_SZ * NH * 4ull)             // 128 KiB
#define OFF_SYNC (OFF_RATE + SZ_RATE)
#define SYNC_WORDS ((u64)2 * NBG * NJG * BBATCH)     // 2048 u64: [par][bg][jg][bb]
#define HS_WORDS   ((u64)NBG * NJG)                  // 256 u64 handshake slots
#define SZ_SYNCHS  ((SYNC_WORDS + HS_WORDS) * 8ull)  // 18,432 B (memset each launch)

// ---------------- agent-scope helpers (MALL; cross-XCD correct) ----------------
__device__ __forceinline__ u64 ld64_agent(const u64* p) {
  return __hip_atomic_load(p, __ATOMIC_RELAXED, __HIP_MEMORY_SCOPE_AGENT);
}
__device__ __forceinline__ void st64_agent(u64* p, u64 v) {
  __hip_atomic_store(p, v, __ATOMIC_RELAXED, __HIP_MEMORY_SCOPE_AGENT);
}
// ---------------- XCD-local helpers (sc0: L1-bypass, served by shared L2) ----------------
__device__ __forceinline__ u64 ld64_xcd(const u64* p) {
  u64 v;
  asm volatile("global_load_dwordx2 %0, %1, off sc0\n\ts_waitcnt vmcnt(0)"
               : "=v"(v) : "v"((u64)(uintptr_t)p) : "memory");
  return v;
}
__device__ __forceinline__ void st64_xcd(u64* p, u64 v) {
  asm volatile("global_store_dwordx2 %0, %1, off sc0"
               :: "v"((u64)(uintptr_t)p), "v"(v) : "memory");
}

// ---------------- kernel 1: I_ext = x @ W_in^T  (fp32 tiled, unchanged) ----------------
// Kept fp32: bf16 I_ext would flip threshold crossings and cascade.
#define GBM 128
#define GBN 128
#define GBK 16
__global__ __launch_bounds__(256) void gemm_in(const float* __restrict__ X,
                                               const float* __restrict__ Win,
                                               float* __restrict__ I) {
  __shared__ float As[GBK][GBM + 4];
  __shared__ float Bs[GBK][GBN + 4];
  const int tid = threadIdx.x;
  const int m0 = blockIdx.x * GBM;
  const int n0 = blockIdx.y * GBN;
  const int tm = tid >> 4, tn = tid & 15;
  const int lr = tid >> 1, lk = (tid & 1) * 8;
  float acc[8][8] = {};
  for (int k0 = 0; k0 < NI; k0 += GBK) {
    float4 a0 = *(const float4*)&X[(size_t)(m0 + lr) * NI + k0 + lk];
    float4 a1 = *(const float4*)&X[(size_t)(m0 + lr) * NI + k0 + lk + 4];
    float4 b0 = *(const float4*)&Win[(size_t)(n0 + lr) * NI + k0 + lk];
    float4 b1 = *(const float4*)&Win[(size_t)(n0 + lr) * NI + k0 + lk + 4];
    As[lk + 0][lr] = a0.x; As[lk + 1][lr] = a0.y; As[lk + 2][lr] = a0.z; As[lk + 3][lr] = a0.w;
    As[lk + 4][lr] = a1.x; As[lk + 5][lr] = a1.y; As[lk + 6][lr] = a1.z; As[lk + 7][lr] = a1.w;
    Bs[lk + 0][lr] = b0.x; Bs[lk + 1][lr] = b0.y; Bs[lk + 2][lr] = b0.z; Bs[lk + 3][lr] = b0.w;
    Bs[lk + 4][lr] = b1.x; Bs[lk + 5][lr] = b1.y; Bs[lk + 6][lr] = b1.z; Bs[lk + 7][lr] = b1.w;
    __syncthreads();
#pragma unroll
    for (int k = 0; k < GBK; ++k) {
      float av[8], bv[8];
      *(float4*)&av[0] = *(const float4*)&As[k][tm * 8];
      *(float4*)&av[4] = *(const float4*)&As[k][tm * 8 + 4];
      *(float4*)&bv[0] = *(const float4*)&Bs[k][tn * 8];
      *(float4*)&bv[4] = *(const float4*)&Bs[k][tn * 8 + 4];
#pragma unroll
      for (int i2 = 0; i2 < 8; ++i2)
#pragma unroll
        for (int j2 = 0; j2 < 8; ++j2) acc[i2][j2] += av[i2] * bv[j2];
    }
    __syncthreads();
  }
#pragma unroll
  for (int i2 = 0; i2 < 8; ++i2) {
    float4 c0 = {acc[i2][0], acc[i2][1], acc[i2][2], acc[i2][3]};
    float4 c1 = {acc[i2][4], acc[i2][5], acc[i2][6], acc[i2][7]};
    *(float4*)&I[(size_t)(m0 + tm * 8 + i2) * NH + n0 + tn * 8] = c0;
    *(float4*)&I[(size_t)(m0 + tm * 8 + i2) * NH + n0 + tn * 8 + 4] = c1;
  }
}

// ---------------- kernel 2: persistent 1000-step scan ----------------
// FP-trajectory identical to R6/R7 (both passed, absmax 4.88e-4): per (b,j),
// rec = [left-fold of spiked i<512, ascending] + [left-fold of spiked i>=512,
// ascending]; state-update op order verbatim. Changes vs R7 are sync-only:
//  * dedicated poll waves (tid 128-255) overlap detection with state/publish
//  * publisher-contiguous layout: block writes 4 u64 = one 32B half-line
//  * XCD-local sc0 fast path, handshake-verified, agent fallback + escalation
//  * sync area memset per launch (no staleness reasoning needed)
// Slot-overwrite safety (parity double buffer) as R7: producer reaches t+2
// publish only after its t+1 poll completed, which needed every consumer's
// t+1 publish, which is after that consumer's t poll read the slot.
__global__ __launch_bounds__(256) void scan_rsnn(const float* __restrict__ Iext,
                                                 const float* __restrict__ Wrec,
                                                 float* __restrict__ rate,
                                                 u64* sync) {
  __shared__ float WL[NH][JBLK + 1];            // WL[i][jl] = Wrec[j0+jl][i]; stride 33 -> 2-way banks (free)
  __shared__ unsigned short slist[BBATCH][NH];  // per-batch spiked-i list, i-ascending
  __shared__ int scnt[BBATCH][2];               // [0]=cntA (i<512), [1]=cnt total
  __shared__ float psumB[128];                  // hi-half partial sums
  __shared__ int fastf;

  const int bid = blockIdx.x;
  const int jg  = bid >> 3;          // 0..31   (bid = jg*8 + bg)
  const int bg  = bid & 7;           // 0..7 == bid%8 == XCD under round-robin
  const int j0  = jg * JBLK;
  const int b0  = bg * BBATCH;
  const int tid = threadIdx.x;
  const int wv  = tid >> 6;
  const int ln  = tid & 63;
  const int bl  = (tid >> 5) & 3;    // batch-local role index
  const int jl  = tid & 31;          // j-local (state/gather) or chunk (poll)

  u64* hs = sync + SYNC_WORDS;

  // ---- handshake part 1: publish my XCD id (agent scope; area memset to 0) ----
  int my_xcc = 0;
  asm volatile("s_getreg_b32 %0, hwreg(HW_REG_XCC_ID)" : "=s"(my_xcc));
  if (tid == 0) st64_agent(&hs[bg * NJG + jg], (u64)(unsigned)my_xcc | (1ull << 32));

  // ---- one-time: stage W columns into LDS (overlaps handshake latency) ----
  for (int k = 0; k < 128; ++k) {
    const int jj = k >> 2;
    const int i  = ((k & 3) << 8) | tid;
    WL[i][jj] = Wrec[(size_t)(j0 + jj) * NH + i];
  }

  const float D1 = 0.90483741803595957f;  // exp(-0.1)
  const float D2 = 0.81873075307798186f;  // exp(-0.2) == decay_syn

  float v = -60.0f, A1 = 0.0f, A2 = 0.0f, rf = 0.0f, h = 0.0f, psc = 0.0f;
  float ip = 0.0f;
  int sc = 0;
  if (tid < 128) ip = Iext[(size_t)(b0 + bl) * NH + j0 + jl];

  // ---- handshake part 2: wave 0 collects all 32 group ids ----
  if (wv == 0) {
    int ok = 1;
    if (ln < 32) {
      const u64* hp = &hs[bg * NJG + ln];
      u64 hv;
      do { hv = ld64_agent(hp); } while ((unsigned)(hv >> 32) != 1u);
      ok = ((int)(unsigned)hv == my_xcc);
    }
    const bool allok = __all(ok);
    if (ln == 0) fastf = allok ? 1 : 0;
  }
  __syncthreads();  // WL ready + fast flag ready
  const bool fast = (fastf != 0);

  for (int t = 0; t < T_STEPS; ++t) {
    const int par = t & 1;
    u64* sbase = sync + (size_t)par * (NBG * NJG * BBATCH) + (size_t)bg * (NJG * BBATCH);
    float ipn = ip;

    if (tid < 128) {
      // ---- state update (op order matches reference exactly) ----
      const float I = ip + psc;
      A1 *= D1; A2 *= D2;
      v = v + ((-60.0f - v) / 20.0f + (I + A1 + A2) / 2.0f);
      const bool inref = rf > 0.0f;
      if (inref) v = -60.0f;
      const bool spike = (!inref) && (v >= -45.0f);
      if (spike) { v = -60.0f; A1 += 1.0f; A2 += -2.0f; rf = 2.0f; sc++; }
      else       { rf = fmaxf(rf - 1.0f, 0.0f); }

      // ---- publish: 4 u64 (one 32B half-line) at [bg][jg][0..3] ----
      const u64 bal = __ballot(spike);  // wave = 2 batches x 32 j
      if ((ln & 31) == 0) {
        const int bb = (wv << 1) | (ln >> 5);   // 0..3
        const unsigned payload = (ln >= 32) ? (unsigned)(bal >> 32) : (unsigned)bal;
        u64* ap = &sbase[(jg << 2) | bb];
        const u64 word = (u64)payload | ((u64)(unsigned)(t + 1) << 32);
        if (fast) st64_xcd(ap, word); else st64_agent(ap, word);
      }
      __builtin_amdgcn_sched_barrier(0);  // publish stays above the prefetch
      // prefetch next step's external current (hidden under poll+gather)
      const int tn2 = (t + 1 < T_STEPS) ? t + 1 : t;
      ipn = Iext[((size_t)tn2 * B_SZ + b0 + bl) * NH + j0 + jl];
    } else {
      // ---- dedicated pollers: word (batch b0+bl, chunk jl) ----
      u64* gp = &sbase[(jl << 2) | bl];
      const unsigned want = (unsigned)(t + 1);
      u64 val;
      if (fast) {
        int tries = 0;
        for (;;) {
          val = (tries < 256) ? ld64_xcd(gp) : ld64_agent(gp);  // escalation: can't hang
          if ((unsigned)(val >> 32) == want) break;
          ++tries;
        }
      } else {
        do { val = ld64_agent(gp); } while ((unsigned)(val >> 32) != want);
      }
      unsigned myw = (unsigned)val;

      // ---- compact bitmap -> index list (2 batches per wave, 32-lane segments) ----
      int inc = __popc(myw);
#pragma unroll
      for (int d = 1; d < 32; d <<= 1) {
        const int y = __shfl_up(inc, d);
        if ((ln & 31) >= d) inc += y;     // segmented inclusive scan
      }
      if ((ln & 31) == 15) scnt[bl][0] = inc;   // cntA: chunks 0-15 = i<512
      if ((ln & 31) == 31) scnt[bl][1] = inc;   // cnt
      int off = inc - __popc(myw);              // exclusive offset
      const int base = jl * 32;                 // chunk jl covers i = 32*jl + bit
      while (myw) {
        const int bit = __builtin_ctz(myw);
        myw &= myw - 1;
        slist[bl][off++] = (unsigned short)(base + bit);
      }
    }
    __syncthreads();  // B1: slist/scnt ready

    // ---- LDS gather, 8-deep MLP, adds applied in list order ----
    // lo half (tid<128): entries [0,cntA) = i<512; hi half: [cntA,cnt).
    float s = 0.0f;
    {
      const int k0 = (tid < 128) ? 0 : scnt[bl][0];
      const int k1 = (tid < 128) ? scnt[bl][0] : scnt[bl][1];
      int k = k0;
      for (; k + 8 <= k1; k += 8) {
        float w8[8];
#pragma unroll
        for (int m = 0; m < 8; ++m) w8[m] = WL[slist[bl][k + m]][jl];
#pragma unroll
        for (int m = 0; m < 8; ++m) s += w8[m];   // in-order adds
      }
      for (; k < k1; ++k) s += WL[slist[bl][k]][jl];
    }
    if (tid >= 128) psumB[tid - 128] = s;
    __syncthreads();  // B2: hi-half sums ready; also guards slist/scnt overwrite

    if (tid < 128) {
      const float rec = s + psumB[tid];   // lo + hi, same association as R6/R7
      h = D2 * h + rec;
      psc = D2 * psc + h;                 // psc uses updated h (matches reference)
      ip = ipn;
    }
  }

  if (tid < 128) rate[(size_t)(b0 + bl) * NH + j0 + jl] = (float)sc / 1000.0f;
}

// ---------------- kernel 3: out = rate @ W_out^T (unchanged) ----------------
__global__ __launch_bounds__(256) void out_gemv(const float* __restrict__ rate,
                                                const float* __restrict__ Wout,
                                                float* __restrict__ out) {
  __shared__ float rs[NH];
  const int b = blockIdx.x, tid = threadIdx.x;
  for (int i = tid; i < NH; i += 256) rs[i] = rate[(size_t)b * NH + i];
  __syncthreads();
  const float* wr = Wout + (size_t)tid * NH;
  float s = 0.0f;
  for (int hh = 0; hh < NH; hh += 4) {
    float4 w4 = *(const float4*)&wr[hh];
    s += rs[hh] * w4.x + rs[hh + 1] * w4.y + rs[hh + 2] * w4.z + rs[hh + 3] * w4.w;
  }
  out[(size_t)b * NO + tid] = s;
}

// ---------------- launch ----------------
extern "C" void kernel_launch(void* const* d_in, const int* in_sizes, int n_in,
                              void* d_out, int out_size, void* d_ws, size_t ws_size,
                              hipStream_t stream) {
  const float* x    = (const float*)d_in[0];
  const float* Win  = (const float*)d_in[1];
  const float* Wrec = (const float*)d_in[2];
  const float* Wout = (const float*)d_in[3];
  float* out = (float*)d_out;

  char* ws = (char*)d_ws;
  float* Iext = (float*)(ws + OFF_IEXT);
  float* rate = (float*)(ws + OFF_RATE);
  u64*   sync = (u64*)(ws + OFF_SYNC);

  // Clear sync + handshake each launch (graph-capturable): tags become 0,
  // wanted tags are >= 1, so no staleness/replay reasoning is needed.
  hipMemsetAsync(ws + OFF_SYNC, 0, SZ_SYNCHS, stream);

  gemm_in<<<dim3((T_STEPS * B_SZ) / GBM, NH / GBN), dim3(256), 0, stream>>>(x, Win, Iext);
  scan_rsnn<<<dim3(NBLK), dim3(256), 0, stream>>>(Iext, Wrec, rate, sync);
  out_gemv<<<dim3(B_SZ), dim3(256), 0, stream>>>(rate, Wout, out);
}

// Round 3
// 3599.951 us; speedup vs baseline: 7.7385x; 7.7385x over previous
//
#include <hip/hip_runtime.h>
#include <stdint.h>

// ---------------- problem constants ----------------
#define T_STEPS 1000
#define B_SZ    32
#define NI      512
#define NH      1024
#define NO      256

#define NSLICE  8     // neuron slices per batch; block (b,s) owns 128 neurons of batch b
#define NBLK    (B_SZ * NSLICE)   // 256 scan blocks

// R9: WTS slices get 16 pad rows; row NH (=1024) of each slice is ZERO and is
// the dummy gather target used to pad spike lists to multiples of 16.
#define NHP     (NH + 16)         // padded rows per slice
#define DUMMY   NH                // index of the zero row
#define BOFF    544               // slist offset of the B-half region (A max 512+pad<=544)

typedef unsigned long long u64;

// ---------------- ws layout (bytes) ----------------
#define OFF_IEXT 0ull
#define SZ_IEXT  ((unsigned long long)T_STEPS * B_SZ * NH * 4ull)   // 131,072,000
#define OFF_WTS  (OFF_IEXT + SZ_IEXT)
#define SZ_WTS   ((unsigned long long)NSLICE * NHP * 128 * 4ull)    // 4.06 MiB, WTS[s][i][jj], i<NHP
#define OFF_RATE (OFF_WTS + SZ_WTS)
#define SZ_RATE  ((unsigned long long)B_SZ * NH * 4ull)             // 128 KiB
#define OFF_SYNC (OFF_RATE + SZ_RATE)
#define SZ_SYNC  ((unsigned long long)2 * B_SZ * NSLICE * 4 * 8ull) // 16 KiB

// ---------------- agent-scope helpers ----------------
__device__ __forceinline__ u64 ld64_agent(const u64* p) {
  return __hip_atomic_load(p, __ATOMIC_RELAXED, __HIP_MEMORY_SCOPE_AGENT);
}
__device__ __forceinline__ void st64_agent(u64* p, u64 v) {
  __hip_atomic_store(p, v, __ATOMIC_RELAXED, __HIP_MEMORY_SCOPE_AGENT);
}

// ---------------- kernel 1: transpose W_rec -> WTS ----------------
// WTS[(s*NHP + i)*128 + jj] = W_rec[(128s+jj)*1024 + i]  (R5-verified mapping,
// slice stride now NHP rows; pad rows [NH,NHP) stay zero from the memset)
__global__ __launch_bounds__(256) void prep_wts(const float* __restrict__ Wrec,
                                                float* __restrict__ WTS) {
  __shared__ float tile[64][65];
  const int tid = threadIdx.x;
  const int j0 = blockIdx.x * 64;
  const int i0 = blockIdx.y * 64;
  const int sl = j0 >> 7;
  const int jjb = j0 & 127;
#pragma unroll
  for (int k = 0; k < 16; ++k) {
    const int idx = k * 256 + tid;
    const int jl = idx >> 6, il = idx & 63;
    tile[jl][il] = Wrec[(size_t)(j0 + jl) * NH + i0 + il];
  }
  __syncthreads();
#pragma unroll
  for (int k = 0; k < 16; ++k) {
    const int idx = k * 256 + tid;
    const int il = idx >> 6, jl = idx & 63;
    WTS[((size_t)(sl * NHP + i0 + il)) * 128 + jjb + jl] = tile[jl][il];
  }
}

// ---------------- kernel 2: I_ext = x @ W_in^T  (fp32 tiled) ----------------
// Kept fp32: bf16 I_ext would flip threshold crossings and cascade.
#define GBM 128
#define GBN 128
#define GBK 16
__global__ __launch_bounds__(256) void gemm_in(const float* __restrict__ X,
                                               const float* __restrict__ Win,
                                               float* __restrict__ I) {
  __shared__ float As[GBK][GBM + 4];
  __shared__ float Bs[GBK][GBN + 4];
  const int tid = threadIdx.x;
  const int m0 = blockIdx.x * GBM;
  const int n0 = blockIdx.y * GBN;
  const int tm = tid >> 4, tn = tid & 15;
  const int lr = tid >> 1, lk = (tid & 1) * 8;
  float acc[8][8] = {};
  for (int k0 = 0; k0 < NI; k0 += GBK) {
    float4 a0 = *(const float4*)&X[(size_t)(m0 + lr) * NI + k0 + lk];
    float4 a1 = *(const float4*)&X[(size_t)(m0 + lr) * NI + k0 + lk + 4];
    float4 b0 = *(const float4*)&Win[(size_t)(n0 + lr) * NI + k0 + lk];
    float4 b1 = *(const float4*)&Win[(size_t)(n0 + lr) * NI + k0 + lk + 4];
    As[lk + 0][lr] = a0.x; As[lk + 1][lr] = a0.y; As[lk + 2][lr] = a0.z; As[lk + 3][lr] = a0.w;
    As[lk + 4][lr] = a1.x; As[lk + 5][lr] = a1.y; As[lk + 6][lr] = a1.z; As[lk + 7][lr] = a1.w;
    Bs[lk + 0][lr] = b0.x; Bs[lk + 1][lr] = b0.y; Bs[lk + 2][lr] = b0.z; Bs[lk + 3][lr] = b0.w;
    Bs[lk + 4][lr] = b1.x; Bs[lk + 5][lr] = b1.y; Bs[lk + 6][lr] = b1.z; Bs[lk + 7][lr] = b1.w;
    __syncthreads();
#pragma unroll
    for (int k = 0; k < GBK; ++k) {
      float av[8], bv[8];
      *(float4*)&av[0] = *(const float4*)&As[k][tm * 8];
      *(float4*)&av[4] = *(const float4*)&As[k][tm * 8 + 4];
      *(float4*)&bv[0] = *(const float4*)&Bs[k][tn * 8];
      *(float4*)&bv[4] = *(const float4*)&Bs[k][tn * 8 + 4];
#pragma unroll
      for (int i2 = 0; i2 < 8; ++i2)
#pragma unroll
        for (int j2 = 0; j2 < 8; ++j2) acc[i2][j2] += av[i2] * bv[j2];
    }
    __syncthreads();
  }
#pragma unroll
  for (int i2 = 0; i2 < 8; ++i2) {
    float4 c0 = {acc[i2][0], acc[i2][1], acc[i2][2], acc[i2][3]};
    float4 c1 = {acc[i2][4], acc[i2][5], acc[i2][6], acc[i2][7]};
    *(float4*)&I[(size_t)(m0 + tm * 8 + i2) * NH + n0 + tn * 8] = c0;
    *(float4*)&I[(size_t)(m0 + tm * 8 + i2) * NH + n0 + tn * 8 + 4] = c1;
  }
}

// ---------------- kernel 3: persistent 1000-step scan, batch-diagonal ----------------
// Structure identical to the proven R6 kernel (3.48 us/step): block (b,sl) owns
// 128 neurons of batch b; sync among the batch's 8 blocks only; agent-scope
// tagged words; wave 2 polls+compacts.  R9 change is gather-only: spike lists
// are padded with DUMMY entries (zero weight row -> exact +0.0 adds) to a
// multiple of 16 plus one extra batch, and the 16-deep gather is double-
// buffered so batch k+1's loads issue before batch k's adds (vmcnt(16), not
// vmcnt(0)).  Fold order per half unchanged -> FP-identical trajectory.
__global__ __launch_bounds__(256) void scan_rsnn(const float* __restrict__ Iext,
                                                 const float* __restrict__ WTS,
                                                 float* __restrict__ rate,
                                                 u64* sync) {
  __shared__ unsigned short slist[1088];  // A: [0,544), B: [544,1088), padded
  __shared__ int scnt[2];                 // padded counts: [0]=A, [1]=B
  __shared__ float psumB[128];

  const int bid = blockIdx.x;
  const int b   = bid >> 3;
  const int sl  = bid & 7;
  const int tid = threadIdx.x;
  const int wv  = tid >> 6;
  const int ln  = tid & 63;
  const int jloc = tid & 127;               // gather target j within slice

  const float* wts = WTS + (size_t)sl * NHP * 128;

  const float D1 = 0.90483741803595957f;    // exp(-0.1)
  const float D2 = 0.81873075307798186f;    // exp(-0.2) == decay_syn

  // state (waves 0-1 only): neuron j = 128*sl + tid, tid<128
  float v = -60.0f, A1 = 0.0f, A2 = 0.0f, rf = 0.0f, h = 0.0f, psc = 0.0f;
  float ip = 0.0f;
  int sc = 0;

  if (tid < 128) ip = Iext[(size_t)b * NH + sl * 128 + tid];

  for (int t = 0; t < T_STEPS; ++t) {
    const int par = t & 1;
    u64* gbase = sync + ((size_t)(par * B_SZ + b)) * (NSLICE * 4);

    if (wv < 2) {
      // ---- state update (op order matches reference exactly) ----
      const float I = ip + psc;
      A1 *= D1; A2 *= D2;
      v = v + ((-60.0f - v) / 20.0f + (I + A1 + A2) / 2.0f);
      const bool inref = rf > 0.0f;
      if (inref) v = -60.0f;
      const bool spike = (!inref) && (v >= -45.0f);
      if (spike) { v = -60.0f; A1 += 1.0f; A2 += -2.0f; rf = 2.0f; sc++; }
      else       { rf = fmaxf(rf - 1.0f, 0.0f); }

      // ballot bit ln = spike(j = 128*sl + 64*wv + ln)
      const u64 bal = __ballot(spike);
      if (ln < 2) {
        const int w = wv * 2 + ln;          // word w covers neurons 128*sl+32w..
        const unsigned payload = ln ? (unsigned)(bal >> 32) : (unsigned)bal;
        st64_agent(&gbase[sl * 4 + w], (u64)payload | ((u64)(unsigned)(t + 1) << 32));
      }
      __builtin_amdgcn_sched_barrier(0);    // keep prefetch below the publish
      // prefetch next step's external current (512B contiguous per block)
      const int tn2 = (t + 1 < T_STEPS) ? t + 1 : t;
      ip = Iext[((size_t)tn2 * B_SZ + b) * NH + sl * 128 + tid];
    } else if (wv == 2) {
      // ---- poll the batch's 32 words (detect == data arrival) ----
      u64 val = 0;
      const u64* gp = &gbase[ln & 31];
      const unsigned want = (unsigned)(t + 1);
      for (;;) {
        if (ln < 32) val = ld64_agent(gp);
        const bool ok = (ln >= 32) || ((unsigned)(val >> 32) == want);
        if (__all(ok)) break;
      }
      // ---- compact bitmap -> split index lists, same (word, bit) order ----
      unsigned myw = (ln < 32) ? (unsigned)val : 0u;
      int inc = __popc(myw);
#pragma unroll
      for (int d = 1; d < 32; d <<= 1) {
        int y = __shfl_up(inc, d);
        if (ln >= d) inc += y;
      }
      const int cntA = __shfl(inc, 15);
      const int cnt  = __shfl(inc, 31);
      if (ln < 32) {
        int off = inc - __popc(myw);        // global exclusive offset
        if (ln >= 16) off += BOFF - cntA;   // B entries go to their own region
        const int base = ln * 32;
        unsigned m = myw;
        while (m) {
          const int bit = __builtin_ctz(m);
          m &= m - 1;
          slist[off++] = (unsigned short)(base + bit);
        }
      }
      // ---- pad each half to multiple of 16 plus one extra dummy batch ----
      // DUMMY points at the slice's zero row: each pad add is s += +0.0f,
      // a bit-exact identity (exact cancellations round to +0, never -0).
      const int cB   = cnt - cntA;
      const int cA16 = ((cntA + 15) & ~15) + 16;   // <= 544
      const int cB16 = ((cB   + 15) & ~15) + 16;   // <= 544
      if (ln < cA16 - cntA) slist[cntA + ln]      = (unsigned short)DUMMY;  // 16..31 pads
      if (ln < cB16 - cB)   slist[BOFF + cB + ln] = (unsigned short)DUMMY;
      if (ln == 0) { scnt[0] = cA16; scnt[1] = cB16; }
    }
    __syncthreads();   // B1: slist/scnt ready

    // ---- tail-free double-buffered gather; adds applied in list order ----
    // A-half (tid<128): region [0,cA16); B-half: [BOFF, BOFF+cB16).
    float s = 0.0f;
    {
      const int kb   = (tid < 128) ? 0 : BOFF;
      const int kEnd = (tid < 128) ? scnt[0] : scnt[1];   // multiple of 16, >=16
      float wv16[16];
#pragma unroll
      for (int m2 = 0; m2 < 16; ++m2)
        wv16[m2] = wts[(size_t)slist[kb + m2] * 128 + jloc];
      for (int k = 16; k < kEnd; k += 16) {
        float nv16[16];
#pragma unroll
        for (int m2 = 0; m2 < 16; ++m2)         // issue batch k before folding k-16
          nv16[m2] = wts[(size_t)slist[kb + k + m2] * 128 + jloc];
#pragma unroll
        for (int m2 = 0; m2 < 16; ++m2) s += wv16[m2];   // in-order adds
#pragma unroll
        for (int m2 = 0; m2 < 16; ++m2) wv16[m2] = nv16[m2];
      }
#pragma unroll
      for (int m2 = 0; m2 < 16; ++m2) s += wv16[m2];     // last batch
    }
    if (tid >= 128) psumB[jloc] = s;
    __syncthreads();   // B2: B-half sums ready; also guards slist overwrite

    if (tid < 128) {
      const float rec = s + psumB[tid];     // same A+B association as R2-R6
      h = D2 * h + rec;
      psc = D2 * psc + h;                   // psc uses updated h (matches reference)
    }
  }

  if (tid < 128) rate[(size_t)b * NH + sl * 128 + tid] = (float)sc / 1000.0f;
}

// ---------------- kernel 4: out = rate @ W_out^T ----------------
__global__ __launch_bounds__(256) void out_gemv(const float* __restrict__ rate,
                                                const float* __restrict__ Wout,
                                                float* __restrict__ out) {
  __shared__ float rs[NH];
  const int b = blockIdx.x, tid = threadIdx.x;
  for (int i = tid; i < NH; i += 256) rs[i] = rate[(size_t)b * NH + i];
  __syncthreads();
  const float* wr = Wout + (size_t)tid * NH;
  float s = 0.0f;
  for (int hh = 0; hh < NH; hh += 4) {
    float4 w4 = *(const float4*)&wr[hh];
    s += rs[hh] * w4.x + rs[hh + 1] * w4.y + rs[hh + 2] * w4.z + rs[hh + 3] * w4.w;
  }
  out[(size_t)b * NO + tid] = s;
}

// ---------------- launch ----------------
extern "C" void kernel_launch(void* const* d_in, const int* in_sizes, int n_in,
                              void* d_out, int out_size, void* d_ws, size_t ws_size,
                              hipStream_t stream) {
  const float* x    = (const float*)d_in[0];
  const float* Win  = (const float*)d_in[1];
  const float* Wrec = (const float*)d_in[2];
  const float* Wout = (const float*)d_in[3];
  float* out = (float*)d_out;

  char* ws = (char*)d_ws;
  float* Iext = (float*)(ws + OFF_IEXT);
  float* WTS  = (float*)(ws + OFF_WTS);
  float* rate = (float*)(ws + OFF_RATE);
  u64*   sync = (u64*)(ws + OFF_SYNC);
  // Sync area: no memset needed -- 0xAA poison tag (0xAAAAAAAA) never equals
  // t+1 <= 1000, and every block publishes before its poll wave can block.

  // Zero WTS so pad rows [NH,NHP) of each slice are 0.0f (the DUMMY target);
  // prep_wts then fills rows [0,NH).  Same-stream ordering serializes these.
  hipMemsetAsync(ws + OFF_WTS, 0, SZ_WTS, stream);

  prep_wts<<<dim3(16, 16), dim3(256), 0, stream>>>(Wrec, WTS);
  gemm_in<<<dim3((T_STEPS * B_SZ) / GBM, NH / GBN), dim3(256), 0, stream>>>(x, Win, Iext);
  scan_rsnn<<<dim3(NBLK), dim3(256), 0, stream>>>(Iext, WTS, rate, sync);
  out_gemv<<<dim3(B_SZ), dim3(256), 0, stream>>>(rate, Wout, out);
}